// Round 1
// baseline (645.350 us; speedup 1.0000x reference)
//
#include <hip/hip_runtime.h>
#include <hip/hip_bf16.h>

#define NE 64
#define HDIM 1024
#define FDIM 2048
#define TDIM 16384

typedef __attribute__((ext_vector_type(8))) short short8;
typedef __attribute__((ext_vector_type(4))) float f32x4;
typedef unsigned short u16;
typedef unsigned int u32;

__device__ __forceinline__ u16 bf16_rne(float f) {
  union { float f; u32 u; } a; a.f = f;
  u32 r = a.u + 0x7fffu + ((a.u >> 16) & 1u);
  return (u16)(r >> 16);
}

// ---- prep: build M-block map (expert, row0, rowend) from tokens_per_expert ----
__global__ void k_prep(const int* __restrict__ tpe, int4* __restrict__ map,
                       int* __restrict__ nblocks) {
  if (threadIdx.x != 0 || blockIdx.x != 0) return;
  int off = 0, nb = 0;
  for (int e = 0; e < NE; ++e) {
    int n = tpe[e];
    for (int r = 0; r < n; r += 128) {
      int re = (r + 128 < n) ? (r + 128) : n;
      map[nb++] = make_int4(e, off + r, off + re, 0);
    }
    off += n;
  }
  *nblocks = nb;
}

// ---- f32 -> bf16 convert, vectorized (16B in / 8B out per thread-iter) ----
__global__ void k_conv(const float4* __restrict__ in, uint2* __restrict__ out, int n4) {
  int stride = gridDim.x * blockDim.x;
  for (int i = blockIdx.x * blockDim.x + threadIdx.x; i < n4; i += stride) {
    float4 v = in[i];
    uint2 o;
    o.x = bf16_rne(v.x) | ((u32)bf16_rne(v.y) << 16);
    o.y = bf16_rne(v.z) | ((u32)bf16_rne(v.w) << 16);
    out[i] = o;
  }
}

// ---- w2 [e][F][H] f32 -> w2t [e][H][F] bf16, 64x64 tiles via padded LDS ----
__global__ __launch_bounds__(256) void k_transpose(const float* __restrict__ w2,
                                                   u16* __restrict__ w2t) {
  __shared__ float lds[64][65];
  const int bid = blockIdx.x;          // e*512 + ft*16 + ht
  const int e = bid >> 9;
  const int rem = bid & 511;
  const int f0 = (rem >> 4) << 6;      // 32 f-tiles of 64
  const int h0 = (rem & 15) << 6;      // 16 h-tiles of 64
  const float* src = w2 + (size_t)e * FDIM * HDIM;
  const int tid = threadIdx.x;
#pragma unroll
  for (int i = 0; i < 4; ++i) {
    int slot = i * 256 + tid;
    int r = slot >> 4, c4 = (slot & 15) << 2;
    float4 v = *(const float4*)(src + (size_t)(f0 + r) * HDIM + h0 + c4);
    lds[r][c4 + 0] = v.x; lds[r][c4 + 1] = v.y;
    lds[r][c4 + 2] = v.z; lds[r][c4 + 3] = v.w;
  }
  __syncthreads();
  u16* dst = w2t + (size_t)e * HDIM * FDIM;
#pragma unroll
  for (int i = 0; i < 4; ++i) {
    int slot = i * 256 + tid;
    int rh = slot >> 4, cf4 = (slot & 15) << 2;
    uint2 o;
    o.x = bf16_rne(lds[cf4 + 0][rh]) | ((u32)bf16_rne(lds[cf4 + 1][rh]) << 16);
    o.y = bf16_rne(lds[cf4 + 2][rh]) | ((u32)bf16_rne(lds[cf4 + 3][rh]) << 16);
    *(uint2*)(dst + (size_t)(h0 + rh) * FDIM + f0 + cf4) = o;
  }
}

// ---- grouped GEMM, m97 structure: 128x128 tile, BK=32, 4 waves, 16x16x32 bf16 MFMA.
// A: bf16 [*][K] (rows grouped by expert).  B: [N][K] per expert — bf16 via
// global_load_lds when !BF32, or f32 reg-staged + converted when BF32.
template<int K, int N, bool GELU, bool BF32>
__global__ __launch_bounds__(256) void k_gemm(
    const u16* __restrict__ A, const void* __restrict__ Bv, void* __restrict__ C,
    const int4* __restrict__ map, const int* __restrict__ nblocks)
{
  if ((int)blockIdx.x >= *nblocks) return;
  const int4 mi = map[blockIdx.x];
  const int e = mi.x, row0 = mi.y, rowend = mi.z;
  const int n0 = blockIdx.y << 7;

  __shared__ u16 smem[8192];   // A tile: elems [0,4096)  B tile: [4096,8192)

  const int tid = threadIdx.x;
  const int wid = tid >> 6, lane = tid & 63;
  const int wr = wid >> 1, wc = wid & 1;
  const int fr = lane & 15, fq = lane >> 4;

  f32x4 acc[4][4];
#pragma unroll
  for (int m = 0; m < 4; ++m)
#pragma unroll
    for (int n = 0; n < 4; ++n) acc[m][n] = (f32x4)0.f;

  const u16*  Bb = (const u16*)Bv + (size_t)e * ((size_t)N * K);
  const float* Bf = (const float*)Bv + (size_t)e * ((size_t)N * K);

  for (int k0 = 0; k0 < K; k0 += 32) {
    // A tile 128x32 bf16 via async global->LDS (16B/lane, 2 issues)
#pragma unroll
    for (int i = 0; i < 2; ++i) {
      int slot = i * 256 + tid;
      int row = row0 + (slot >> 2);
      row = row < TDIM ? row : TDIM - 1;    // tail blocks: clamp, garbage rows unused
      const u16* g = A + (size_t)row * K + k0 + (slot & 3) * 8;
      __builtin_amdgcn_global_load_lds(
          (const __attribute__((address_space(1))) u32*)g,
          (__attribute__((address_space(3))) u32*)(smem + i * 2048 + wid * 512),
          16, 0, 0);
    }
    if constexpr (!BF32) {
#pragma unroll
      for (int i = 0; i < 2; ++i) {
        int slot = i * 256 + tid;
        const u16* g = Bb + (size_t)(n0 + (slot >> 2)) * K + k0 + (slot & 3) * 8;
        __builtin_amdgcn_global_load_lds(
            (const __attribute__((address_space(1))) u32*)g,
            (__attribute__((address_space(3))) u32*)(smem + 4096 + i * 2048 + wid * 512),
            16, 0, 0);
      }
    } else {
      // B tile 128x32 f32 -> bf16: coalesced float4 loads, 8B LDS writes
      float4 v[4];
#pragma unroll
      for (int i = 0; i < 4; ++i) {
        int slot = i * 256 + tid;
        v[i] = *(const float4*)(Bf + (size_t)(n0 + (slot >> 3)) * K + k0 + (slot & 7) * 4);
      }
#pragma unroll
      for (int i = 0; i < 4; ++i) {
        int slot = i * 256 + tid;
        uint2 o;
        o.x = bf16_rne(v[i].x) | ((u32)bf16_rne(v[i].y) << 16);
        o.y = bf16_rne(v[i].z) | ((u32)bf16_rne(v[i].w) << 16);
        *(uint2*)(smem + 4096 + (slot >> 3) * 32 + (slot & 7) * 4) = o;
      }
    }
    __syncthreads();   // drains vmcnt (global_load_lds) + lgkmcnt (ds_write)

    short8 av[4], bv[4];
#pragma unroll
    for (int m = 0; m < 4; ++m)
      av[m] = *(const short8*)(smem + (wr * 64 + m * 16 + fr) * 32 + fq * 8);
#pragma unroll
    for (int n = 0; n < 4; ++n)
      bv[n] = *(const short8*)(smem + 4096 + (wc * 64 + n * 16 + fr) * 32 + fq * 8);
#pragma unroll
    for (int m = 0; m < 4; ++m)
#pragma unroll
      for (int n = 0; n < 4; ++n)
        acc[m][n] = __builtin_amdgcn_mfma_f32_16x16x32_bf16(av[m], bv[n], acc[m][n], 0, 0, 0);
    __syncthreads();
  }

  // epilogue: C/D layout row=(lane>>4)*4+j, col=lane&15 (m89-verified)
#pragma unroll
  for (int m = 0; m < 4; ++m) {
    const int rb = row0 + wr * 64 + m * 16 + fq * 4;
#pragma unroll
    for (int n = 0; n < 4; ++n) {
      const int col = n0 + wc * 64 + n * 16 + fr;
#pragma unroll
      for (int j = 0; j < 4; ++j) {
        int r = rb + j;
        if (r < rowend) {
          float vv = acc[m][n][j];
          if constexpr (GELU) {
            vv = 0.5f * vv * (1.f + erff(vv * 0.70710678118654752f));
            ((u16*)C)[(size_t)r * N + col] = bf16_rne(vv);
          } else {
            ((float*)C)[(size_t)r * N + col] = vv;
          }
        }
      }
    }
  }
}

extern "C" void kernel_launch(void* const* d_in, const int* in_sizes, int n_in,
                              void* d_out, int out_size, void* d_ws, size_t ws_size,
                              hipStream_t stream) {
  const float* x  = (const float*)d_in[0];
  const float* w1 = (const float*)d_in[1];
  const float* w2 = (const float*)d_in[2];
  const int*  tpe = (const int*)d_in[3];

  char* ws = (char*)d_ws;
  int4* map     = (int4*)ws;                       // up to 192 entries (4KB region)
  int*  nblocks = (int*)(ws + 4096);
  u16*  xb      = (u16*)(ws + 8192);               // T*H bf16   = 32MB
  u16*  hb      = xb + (size_t)TDIM * HDIM;        // T*F bf16   = 64MB
  u16*  w2t     = hb + (size_t)TDIM * FDIM;        // NE*H*F bf16 = 256MB
  // total ws requirement ~352MB

  k_prep<<<1, 64, 0, stream>>>(tpe, map, nblocks);
  k_conv<<<2048, 256, 0, stream>>>((const float4*)x, (uint2*)xb, (TDIM * HDIM) / 4);
  k_transpose<<<NE * 512, 256, 0, stream>>>(w2, w2t);
  // GEMM1: h = gelu(x @ w1^T)   A=[T][1024] bf16, B=w1 f32 [F][H] (N x K)
  k_gemm<HDIM, FDIM, true,  true ><<<dim3(192, FDIM / 128), 256, 0, stream>>>(
      xb, (const void*)w1, (void*)hb, map, nblocks);
  // GEMM2: out = h @ w2         A=[T][2048] bf16, B=w2t bf16 [H][F] (N x K)
  k_gemm<FDIM, HDIM, false, false><<<dim3(192, HDIM / 128), 256, 0, stream>>>(
      hb, (const void*)w2t, d_out, map, nblocks);
}

// Round 2
// 541.458 us; speedup vs baseline: 1.1919x; 1.1919x over previous
//
#include <hip/hip_runtime.h>
#include <hip/hip_bf16.h>

#define NE 64
#define HDIM 1024
#define FDIM 2048
#define TDIM 16384

typedef __attribute__((ext_vector_type(8))) short short8;
typedef __attribute__((ext_vector_type(4))) float f32x4;
typedef unsigned short u16;
typedef unsigned int u32;

__device__ __forceinline__ u16 bf16_rne(float f) {
  union { float f; u32 u; } a; a.f = f;
  u32 r = a.u + 0x7fffu + ((a.u >> 16) & 1u);
  return (u16)(r >> 16);
}

// ---- prep: build M-block map (expert, row0, rowend) from tokens_per_expert ----
__global__ void k_prep(const int* __restrict__ tpe, int4* __restrict__ map,
                       int* __restrict__ nblocks) {
  if (threadIdx.x != 0 || blockIdx.x != 0) return;
  int off = 0, nb = 0;
  for (int e = 0; e < NE; ++e) {
    int n = tpe[e];
    for (int r = 0; r < n; r += 128) {
      int re = (r + 128 < n) ? (r + 128) : n;
      map[nb++] = make_int4(e, off + r, off + re, 0);
    }
    off += n;
  }
  *nblocks = nb;
}

// ---- f32 -> bf16 convert, vectorized (16B in / 8B out per thread-iter) ----
__global__ void k_conv(const float4* __restrict__ in, uint2* __restrict__ out, int n4) {
  int stride = gridDim.x * blockDim.x;
  for (int i = blockIdx.x * blockDim.x + threadIdx.x; i < n4; i += stride) {
    float4 v = in[i];
    uint2 o;
    o.x = bf16_rne(v.x) | ((u32)bf16_rne(v.y) << 16);
    o.y = bf16_rne(v.z) | ((u32)bf16_rne(v.w) << 16);
    out[i] = o;
  }
}

// ---- grouped GEMM, m97 structure: 128x128 tile, BK=32, 4 waves, 16x16x32 bf16 MFMA.
// A: bf16 [*][K] rows grouped by expert, staged via global_load_lds (linear LDS).
// B per expert, f32, converted on the fly:
//   BMODE==1: B stored [N][K] (k-contig)  -> float4 loads, direct LDS write
//   BMODE==2: B stored [K][N] (n-contig)  -> n-coalesced scalar loads, transposed
//             LDS write (thread owns one n-column, 16 consecutive k -> b128 write)
// LDS B tile rows padded to 40 u16 (80B): bank starts cycle all 8 groups -> no conflicts.
template<int K, int N, bool GELU, int BMODE>
__global__ __launch_bounds__(256) void k_gemm(
    const u16* __restrict__ A, const float* __restrict__ Bf, void* __restrict__ C,
    const int4* __restrict__ map, const int* __restrict__ nblocks)
{
  if ((int)blockIdx.x >= *nblocks) return;
  const int4 mi = map[blockIdx.x];
  const int e = mi.x, row0 = mi.y, rowend = mi.z;
  const int n0 = blockIdx.y << 7;

  __shared__ u16 smem[4096 + 128 * 40];   // A: [0,4096) linear [128][32]; B: 40-u16 rows

  const int tid = threadIdx.x;
  const int wid = tid >> 6, lane = tid & 63;
  const int wr = wid >> 1, wc = wid & 1;
  const int fr = lane & 15, fq = lane >> 4;

  f32x4 acc[4][4];
#pragma unroll
  for (int m = 0; m < 4; ++m)
#pragma unroll
    for (int n = 0; n < 4; ++n) acc[m][n] = (f32x4)0.f;

  const float* B = Bf + (size_t)e * ((size_t)N * K);

  for (int k0 = 0; k0 < K; k0 += 32) {
    // A tile 128x32 bf16 via async global->LDS (16B/lane, 2 issues)
#pragma unroll
    for (int i = 0; i < 2; ++i) {
      int slot = i * 256 + tid;
      int row = row0 + (slot >> 2);
      row = row < TDIM ? row : TDIM - 1;    // tail blocks: clamp, garbage rows unused
      const u16* g = A + (size_t)row * K + k0 + (slot & 3) * 8;
      __builtin_amdgcn_global_load_lds(
          (const __attribute__((address_space(1))) u32*)g,
          (__attribute__((address_space(3))) u32*)(smem + i * 2048 + wid * 512),
          16, 0, 0);
    }
    if constexpr (BMODE == 1) {
      // B [N][K]: coalesced float4 loads (8 lanes x 16B per n-row), 8B LDS writes
      float4 v[4];
#pragma unroll
      for (int i = 0; i < 4; ++i) {
        int slot = i * 256 + tid;
        v[i] = *(const float4*)(B + (size_t)(n0 + (slot >> 3)) * K + k0 + (slot & 7) * 4);
      }
#pragma unroll
      for (int i = 0; i < 4; ++i) {
        int slot = i * 256 + tid;
        uint2 o;
        o.x = bf16_rne(v[i].x) | ((u32)bf16_rne(v[i].y) << 16);
        o.y = bf16_rne(v[i].z) | ((u32)bf16_rne(v[i].w) << 16);
        *(uint2*)(smem + 4096 + (slot >> 3) * 40 + (slot & 7) * 4) = o;
      }
    } else {
      // B [K][N]: thread owns column n = (wid&1)*64+lane, k-half g = wid>>1.
      // 16 scalar f32 loads, n-coalesced (64 lanes x 4B contiguous per k-row).
      const int nn = ((wid & 1) << 6) | lane;
      const int g  = wid >> 1;
      const float* src = B + (size_t)(k0 + g * 16) * N + n0 + nn;
      float v[16];
#pragma unroll
      for (int i = 0; i < 16; ++i) v[i] = src[(size_t)i * N];
      short8 lo, hi;
#pragma unroll
      for (int i = 0; i < 8; ++i) {
        lo[i] = (short)bf16_rne(v[i]);
        hi[i] = (short)bf16_rne(v[i + 8]);
      }
      *(short8*)(smem + 4096 + nn * 40 + g * 16 + 0) = lo;   // byte: n*80 + g*32, 16B-aligned
      *(short8*)(smem + 4096 + nn * 40 + g * 16 + 8) = hi;
    }
    __syncthreads();   // drains vmcnt (global_load_lds) + lgkmcnt (ds_write)

    short8 av[4], bv[4];
#pragma unroll
    for (int m = 0; m < 4; ++m)
      av[m] = *(const short8*)(smem + (wr * 64 + m * 16 + fr) * 32 + fq * 8);
#pragma unroll
    for (int n = 0; n < 4; ++n)
      bv[n] = *(const short8*)(smem + 4096 + (wc * 64 + n * 16 + fr) * 40 + fq * 8);
#pragma unroll
    for (int m = 0; m < 4; ++m)
#pragma unroll
      for (int n = 0; n < 4; ++n)
        acc[m][n] = __builtin_amdgcn_mfma_f32_16x16x32_bf16(av[m], bv[n], acc[m][n], 0, 0, 0);
    __syncthreads();
  }

  // epilogue: C/D layout row=(lane>>4)*4+j, col=lane&15 (m89-verified)
#pragma unroll
  for (int m = 0; m < 4; ++m) {
    const int rb = row0 + wr * 64 + m * 16 + fq * 4;
#pragma unroll
    for (int n = 0; n < 4; ++n) {
      const int col = n0 + wc * 64 + n * 16 + fr;
#pragma unroll
      for (int j = 0; j < 4; ++j) {
        int r = rb + j;
        if (r < rowend) {
          float vv = acc[m][n][j];
          if constexpr (GELU) {
            vv = 0.5f * vv * (1.f + erff(vv * 0.70710678118654752f));
            ((u16*)C)[(size_t)r * N + col] = bf16_rne(vv);
          } else {
            ((float*)C)[(size_t)r * N + col] = vv;
          }
        }
      }
    }
  }
}

extern "C" void kernel_launch(void* const* d_in, const int* in_sizes, int n_in,
                              void* d_out, int out_size, void* d_ws, size_t ws_size,
                              hipStream_t stream) {
  const float* x  = (const float*)d_in[0];
  const float* w1 = (const float*)d_in[1];
  const float* w2 = (const float*)d_in[2];
  const int*  tpe = (const int*)d_in[3];

  char* ws = (char*)d_ws;
  int4* map     = (int4*)ws;                       // up to 192 entries
  int*  nblocks = (int*)(ws + 4096);
  u16*  xb      = (u16*)(ws + 8192);               // T*H bf16 = 32MB
  u16*  hb      = xb + (size_t)TDIM * HDIM;        // T*F bf16 = 64MB
  // total ws requirement ~96MB

  k_prep<<<1, 64, 0, stream>>>(tpe, map, nblocks);
  k_conv<<<2048, 256, 0, stream>>>((const float4*)x, (uint2*)xb, (TDIM * HDIM) / 4);
  // GEMM1: h = gelu(x @ w1^T)   A=[T][1024] bf16, B=w1 f32 [F][H] = [N][K]
  k_gemm<HDIM, FDIM, true,  1><<<dim3(192, FDIM / 128), 256, 0, stream>>>(
      xb, w1, (void*)hb, map, nblocks);
  // GEMM2: out = h @ w2         A=[T][2048] bf16, B=w2 f32 [F][H] = [K][N]
  k_gemm<FDIM, HDIM, false, 2><<<dim3(192, HDIM / 128), 256, 0, stream>>>(
      hb, w2, d_out, map, nblocks);
}